// Round 1
// baseline (366.298 us; speedup 1.0000x reference)
//
#include <hip/hip_runtime.h>

// Problem constants (from reference): features [C=32, N], coords [N,3]=(b,h,w),
// output [B, C, NH=64, NW=256] float32.
#define CC 32
#define NHH 64
#define NWW 256
#define PLANE (NHH * NWW)        // 16384
#define BSTRIDE (CC * PLANE)     // 524288

__global__ void pss_scatter(const float* __restrict__ features,
                            const int* __restrict__ coords,
                            float* __restrict__ out, int N) {
    int n = blockIdx.x * blockDim.x + threadIdx.x;
    if (n >= N) return;
    int b = coords[3 * n + 0];
    int h = coords[3 * n + 1];
    int w = coords[3 * n + 2];
    // base index of (b, c=0, h, w) in out
    int base = b * BSTRIDE + h * NWW + w;
#pragma unroll
    for (int c = 0; c < CC; ++c) {
        // features read: for fixed c, consecutive lanes (n) are contiguous -> coalesced.
        // out write: scattered 4B store, stride PLANE between channels.
        out[base + c * PLANE] = features[c * N + n];
    }
}

extern "C" void kernel_launch(void* const* d_in, const int* in_sizes, int n_in,
                              void* d_out, int out_size, void* d_ws, size_t ws_size,
                              hipStream_t stream) {
    const float* features = (const float*)d_in[0];
    const int* coords = (const int*)d_in[1];
    float* out = (float*)d_out;

    const int N = in_sizes[1] / 3;  // coords is [N,3]

    // Zero the canvas (empty cells must be 0). Graph-capture-safe async memset.
    hipMemsetAsync(d_out, 0, (size_t)out_size * sizeof(float), stream);

    const int threads = 256;
    const int blocks = (N + threads - 1) / threads;
    pss_scatter<<<blocks, threads, 0, stream>>>(features, coords, out, N);
}

// Round 2
// 141.127 us; speedup vs baseline: 2.5955x; 2.5955x over previous
//
#include <hip/hip_runtime.h>

// Problem constants: features [C=32, N], coords [N,3]=(b,h,w),
// output [B=64, C=32, NH=64, NW=256] float32.
#define CC 32
#define BB 64
#define NHH 64
#define NWW 256
#define PLANE (NHH * NWW)        // 16384 cells per batch
#define BSTRIDE (CC * PLANE)     // 524288 floats per batch in out
#define NCELLS (BB * PLANE)      // 1048576 total cells

// ---------- Fallback (round-1) direct scatter ----------
__global__ void pss_scatter_direct(const float* __restrict__ features,
                                   const int* __restrict__ coords,
                                   float* __restrict__ out, int N) {
    int n = blockIdx.x * blockDim.x + threadIdx.x;
    if (n >= N) return;
    int b = coords[3 * n + 0];
    int h = coords[3 * n + 1];
    int w = coords[3 * n + 2];
    int base = b * BSTRIDE + h * NWW + w;
#pragma unroll
    for (int c = 0; c < CC; ++c)
        out[base + c * PLANE] = features[c * N + n];
}

// ---------- K2: scatter feature columns into [cell][C] staging ----------
// Reads: features[c*N + n] — for fixed c, lanes read consecutive n -> coalesced.
// Writes: staging[cell*32 .. +32] — one contiguous 128B row per voxel (2 full
// 64B lines, no write amplification). flags[cell] = 1.
__global__ void pss_stage(const float* __restrict__ features,
                          const int* __restrict__ coords,
                          float* __restrict__ staging,
                          unsigned char* __restrict__ flags, int N) {
    int n = blockIdx.x * blockDim.x + threadIdx.x;
    if (n >= N) return;
    int b = coords[3 * n + 0];
    int h = coords[3 * n + 1];
    int w = coords[3 * n + 2];
    int cell = b * PLANE + h * NWW + w;

    float f[CC];
#pragma unroll
    for (int c = 0; c < CC; ++c)
        f[c] = features[(size_t)c * N + n];

    float4* dst = (float4*)(staging + (size_t)cell * CC);
#pragma unroll
    for (int k = 0; k < CC / 4; ++k)
        dst[k] = make_float4(f[4 * k], f[4 * k + 1], f[4 * k + 2], f[4 * k + 3]);

    flags[cell] = 1;
}

// ---------- K3: masked transpose staging [cell][C] -> out [B][C][H][W] ----------
// One block per (b,h) row: 256 cells x 32 channels = 8192 floats = 32KB slab.
// Load slab fully coalesced, LDS-transpose (pad 33), masked coalesced store.
__global__ __launch_bounds__(256) void pss_emit(const float* __restrict__ staging,
                                                const unsigned char* __restrict__ flags,
                                                float* __restrict__ out) {
    __shared__ float lds[NWW * (CC + 1)];  // 256 * 33 floats = 33792 B

    int row = blockIdx.x;          // 0 .. B*NH-1
    int b = row / NHH;
    int h = row % NHH;
    int t = threadIdx.x;           // 0..255

    size_t slab = ((size_t)b * PLANE + (size_t)h * NWW) * CC;  // float index

    // Coalesced linear load of the 8192-float slab; element e = t + 256*k.
    // e -> (w = e/32, c = e%32). c = t&31 (const per thread), w = (t>>5) + 8k.
    int c0 = t & 31;
    int w0 = t >> 5;
#pragma unroll
    for (int k = 0; k < CC; ++k) {
        int e = t + 256 * k;
        float v = staging[slab + e];
        int w = w0 + 8 * k;
        lds[w * (CC + 1) + c0] = v;   // banks (w+c)%32: 2 lanes/bank -> free
    }

    // Validity for this thread's output column w = t.
    float m = (float)flags[(size_t)b * PLANE + (size_t)h * NWW + t];

    __syncthreads();

    size_t obase = (size_t)b * BSTRIDE + (size_t)h * NWW + t;
#pragma unroll
    for (int c = 0; c < CC; ++c) {
        float v = lds[t * (CC + 1) + c];   // banks (t+c)%32 -> conflict-free
        out[obase + (size_t)c * PLANE] = v * m;  // masked; poison*0 = 0 (0xAA.. is a valid finite float)
    }
}

extern "C" void kernel_launch(void* const* d_in, const int* in_sizes, int n_in,
                              void* d_out, int out_size, void* d_ws, size_t ws_size,
                              hipStream_t stream) {
    const float* features = (const float*)d_in[0];
    const int* coords = (const int*)d_in[1];
    float* out = (float*)d_out;
    const int N = in_sizes[1] / 3;

    const size_t staging_bytes = (size_t)NCELLS * CC * sizeof(float); // 134,217,728
    const size_t flags_bytes = (size_t)NCELLS;                        // 1,048,576

    if (ws_size < staging_bytes + flags_bytes) {
        // Fallback: direct scatter (correct, slower).
        hipMemsetAsync(d_out, 0, (size_t)out_size * sizeof(float), stream);
        int blocks = (N + 255) / 256;
        pss_scatter_direct<<<blocks, 256, 0, stream>>>(features, coords, out, N);
        return;
    }

    float* staging = (float*)d_ws;
    unsigned char* flags = (unsigned char*)d_ws + staging_bytes;

    // Only the 1MB flag array needs zeroing; out is fully overwritten by K3.
    hipMemsetAsync(flags, 0, flags_bytes, stream);

    int blocks = (N + 255) / 256;
    pss_stage<<<blocks, 256, 0, stream>>>(features, coords, staging, flags, N);

    pss_emit<<<BB * NHH, 256, 0, stream>>>(staging, flags, out);
}

// Round 3
// 127.784 us; speedup vs baseline: 2.8665x; 1.1044x over previous
//
#include <hip/hip_runtime.h>

// Problem constants: features [C=32, N], coords [N,3]=(b,h,w),
// output [B=64, C=32, NH=64, NW=256] float32.
#define CC 32
#define BB 64
#define NHH 64
#define NWW 256
#define PLANE (NHH * NWW)        // 16384 cells per batch
#define BSTRIDE (CC * PLANE)     // 524288 floats per batch in out
#define NCELLS (BB * PLANE)      // 1048576 total cells

// ---------- Fallback (round-1) direct scatter ----------
__global__ void pss_scatter_direct(const float* __restrict__ features,
                                   const int* __restrict__ coords,
                                   float* __restrict__ out, int N) {
    int n = blockIdx.x * blockDim.x + threadIdx.x;
    if (n >= N) return;
    int b = coords[3 * n + 0];
    int h = coords[3 * n + 1];
    int w = coords[3 * n + 2];
    int base = b * BSTRIDE + h * NWW + w;
#pragma unroll
    for (int c = 0; c < CC; ++c)
        out[base + c * PLANE] = features[c * N + n];
}

// ---------- K1: transpose features [C][N] -> featT [N][C], fused invmap ----------
// Reads features coalesced (fixed c, consecutive n across lanes).
// Writes featT as fully-linear float4 stream (sequential HBM traffic).
// Also scatters invmap[cell] = n+1 (4B random writes into a 4MB region; L3-absorbed).
__global__ __launch_bounds__(256) void pss_transpose_invmap(
        const float* __restrict__ features, const int* __restrict__ coords,
        float* __restrict__ featT, int* __restrict__ invmap, int N) {
    __shared__ float lds[256 * (CC + 1)];  // 256 n-rows x 33 -> 33792 B

    int t = threadIdx.x;
    int n0 = blockIdx.x * 256;
    int n = n0 + t;

    // invmap scatter (memset to 0 happens before this kernel; 0 == empty)
    if (n < N) {
        int b = coords[3 * n + 0];
        int h = coords[3 * n + 1];
        int w = coords[3 * n + 2];
        invmap[b * PLANE + h * NWW + w] = n + 1;
    }

    // Load tile: for fixed c=k, lanes read consecutive n -> coalesced.
    // lds[t*33 + k]: bank (t+k)%32 -> conflict-free across lanes.
#pragma unroll
    for (int k = 0; k < CC; ++k) {
        float v = (n < N) ? features[(size_t)k * N + n] : 0.0f;
        lds[t * (CC + 1) + k] = v;
    }
    __syncthreads();

    // Store: float4-linear over the tile. float4 index within tile = t + 256*j.
    // tile float4 (idx) -> local row nl = idx>>3, quad cq = idx&7.
    float4* dstv = (float4*)featT;
#pragma unroll
    for (int j = 0; j < 8; ++j) {
        int idx = t + 256 * j;
        int nl = idx >> 3;
        int cq = idx & 7;
        if (n0 + nl < N) {
            float4 v;
            v.x = lds[nl * (CC + 1) + 4 * cq + 0];
            v.y = lds[nl * (CC + 1) + 4 * cq + 1];
            v.z = lds[nl * (CC + 1) + 4 * cq + 2];
            v.w = lds[nl * (CC + 1) + 4 * cq + 3];
            dstv[(size_t)n0 * (CC / 4) + idx] = v;  // fully sequential across lanes
        }
    }
}

// ---------- K2: gather featT rows per cell, emit out coalesced ----------
// Block per (b,h) row: thread t = cell w=t. invmap read coalesced; featT row
// read as 8x float4 (random 128B row, expected L3-resident). LDS transpose
// (pad 33), fully-coalesced masked output stores. Out is fully written -> no
// output memset required.
__global__ __launch_bounds__(256) void pss_gather_emit(
        const float* __restrict__ featT, const int* __restrict__ invmap,
        float* __restrict__ out) {
    __shared__ float lds[NWW * (CC + 1)];  // 256 * 33 floats

    int row = blockIdx.x;          // 0 .. B*NH-1  (row = b*NHH + h)
    int b = row / NHH;
    int h = row % NHH;
    int t = threadIdx.x;           // 0..255 = w

    int inv = invmap[(size_t)row * NWW + t];  // coalesced 1KB per block

    if (inv > 0) {
        const float4* src = (const float4*)(featT + (size_t)(inv - 1) * CC);
#pragma unroll
        for (int k = 0; k < CC / 4; ++k) {
            float4 v = src[k];
            lds[t * (CC + 1) + 4 * k + 0] = v.x;
            lds[t * (CC + 1) + 4 * k + 1] = v.y;
            lds[t * (CC + 1) + 4 * k + 2] = v.z;
            lds[t * (CC + 1) + 4 * k + 3] = v.w;
        }
    } else {
#pragma unroll
        for (int k = 0; k < CC; ++k)
            lds[t * (CC + 1) + k] = 0.0f;
    }

    __syncthreads();

    size_t obase = (size_t)b * BSTRIDE + (size_t)h * NWW + t;
#pragma unroll
    for (int c = 0; c < CC; ++c) {
        float v = lds[t * (CC + 1) + c];  // bank (t+c)%32 -> conflict-free
        out[obase + (size_t)c * PLANE] = v;
    }
}

extern "C" void kernel_launch(void* const* d_in, const int* in_sizes, int n_in,
                              void* d_out, int out_size, void* d_ws, size_t ws_size,
                              hipStream_t stream) {
    const float* features = (const float*)d_in[0];
    const int* coords = (const int*)d_in[1];
    float* out = (float*)d_out;
    const int N = in_sizes[1] / 3;

    const size_t invmap_bytes = (size_t)NCELLS * sizeof(int);       // 4 MiB
    const size_t featT_bytes = (size_t)N * CC * sizeof(float);      // ~115 MB

    if (ws_size < invmap_bytes + featT_bytes) {
        // Fallback: direct scatter (correct, slower).
        hipMemsetAsync(d_out, 0, (size_t)out_size * sizeof(float), stream);
        int blocks = (N + 255) / 256;
        pss_scatter_direct<<<blocks, 256, 0, stream>>>(features, coords, out, N);
        return;
    }

    int* invmap = (int*)d_ws;
    float* featT = (float*)((char*)d_ws + invmap_bytes);

    // Zero invmap (0 == empty cell). 4 MiB memset, cheap.
    hipMemsetAsync(invmap, 0, invmap_bytes, stream);

    int blocks = (N + 255) / 256;
    pss_transpose_invmap<<<blocks, 256, 0, stream>>>(features, coords, featT,
                                                     invmap, N);

    pss_gather_emit<<<BB * NHH, 256, 0, stream>>>(featT, invmap, out);
}

// Round 4
// 114.421 us; speedup vs baseline: 3.2013x; 1.1168x over previous
//
#include <hip/hip_runtime.h>

// Problem constants: features [C=32, N], coords [N,3]=(b,h,w),
// output [B=64, C=32, NH=64, NW=256] float32.
#define CC 32
#define BB 64
#define NHH 64
#define NWW 256
#define PLANE (NHH * NWW)        // 16384 cells per batch
#define BSTRIDE (CC * PLANE)     // 524288 floats per batch in out
#define NCELLS (BB * PLANE)      // 1048576 total cells

// ---------- Fallback (round-1) direct scatter ----------
__global__ void pss_scatter_direct(const float* __restrict__ features,
                                   const int* __restrict__ coords,
                                   float* __restrict__ out, int N) {
    int n = blockIdx.x * blockDim.x + threadIdx.x;
    if (n >= N) return;
    int b = coords[3 * n + 0];
    int h = coords[3 * n + 1];
    int w = coords[3 * n + 2];
    int base = b * BSTRIDE + h * NWW + w;
#pragma unroll
    for (int c = 0; c < CC; ++c)
        out[base + c * PLANE] = features[c * N + n];
}

// ---------- K0: invmap scatter (tiny): invmap[cell] = n+1 ----------
__global__ void pss_invmap(const int* __restrict__ coords,
                           int* __restrict__ invmap, int N) {
    int n = blockIdx.x * blockDim.x + threadIdx.x;
    if (n >= N) return;
    int b = coords[3 * n + 0];
    int h = coords[3 * n + 1];
    int w = coords[3 * n + 2];
    invmap[b * PLANE + h * NWW + w] = n + 1;
}

// ---------- K1: transpose features [C][N] -> featT [N][C] ----------
// 128 threads, tile 128n x 32c. LDS 16.9KB -> ~9 blocks/CU for latency overlap.
// Loads: 8x float4 per thread (coalesced 512B runs per half-wave).
// Stores: 8x float4 per thread, fully-linear stream.
__global__ __launch_bounds__(128) void pss_transpose(
        const float* __restrict__ features, float* __restrict__ featT, int N) {
    __shared__ float lds[CC][132];  // c-major; stride 132 dwords (16B-aligned, ~conflict-free writes)

    int t = threadIdx.x;
    int n0 = blockIdx.x * 128;

    int kbase = t >> 5;           // 0..3
    int nl4 = (t & 31) << 2;      // 0,4,...,124
    int n = n0 + nl4;
    bool ok = (n < N);            // N % 4 == 0, so n<N implies n+3<N

#pragma unroll
    for (int j = 0; j < 8; ++j) {
        int k = kbase + 4 * j;    // covers c = 0..31 across j
        float4 v = make_float4(0.f, 0.f, 0.f, 0.f);
        if (ok) v = *(const float4*)&features[(size_t)k * N + n];
        *(float4*)&lds[k][nl4] = v;   // ds_write_b128, uniform banks
    }

    __syncthreads();

    // Store: flat float4 index within tile = t + 128*j (0..1023).
    // idx -> local row nl = idx>>3, c-quad cq = idx&7.
    float4* dstv = (float4*)featT;
#pragma unroll
    for (int j = 0; j < 8; ++j) {
        int idx = t + 128 * j;
        int nl = idx >> 3;
        int cq = idx & 7;
        if (n0 + nl < N) {
            float4 v;
            v.x = lds[4 * cq + 0][nl];
            v.y = lds[4 * cq + 1][nl];
            v.z = lds[4 * cq + 2][nl];
            v.w = lds[4 * cq + 3][nl];
            dstv[(size_t)n0 * (CC / 4) + idx] = v;  // fully sequential across lanes
        }
    }
}

// ---------- K2: gather featT rows per cell, emit out coalesced ----------
__global__ __launch_bounds__(256) void pss_gather_emit(
        const float* __restrict__ featT, const int* __restrict__ invmap,
        float* __restrict__ out) {
    __shared__ float lds[NWW * (CC + 1)];  // 256 * 33 floats

    int row = blockIdx.x;          // 0 .. B*NH-1  (row = b*NHH + h)
    int b = row / NHH;
    int h = row % NHH;
    int t = threadIdx.x;           // 0..255 = w

    int inv = invmap[(size_t)row * NWW + t];  // coalesced 1KB per block

    if (inv > 0) {
        const float4* src = (const float4*)(featT + (size_t)(inv - 1) * CC);
#pragma unroll
        for (int k = 0; k < CC / 4; ++k) {
            float4 v = src[k];
            lds[t * (CC + 1) + 4 * k + 0] = v.x;
            lds[t * (CC + 1) + 4 * k + 1] = v.y;
            lds[t * (CC + 1) + 4 * k + 2] = v.z;
            lds[t * (CC + 1) + 4 * k + 3] = v.w;
        }
    } else {
#pragma unroll
        for (int k = 0; k < CC; ++k)
            lds[t * (CC + 1) + k] = 0.0f;
    }

    __syncthreads();

    size_t obase = (size_t)b * BSTRIDE + (size_t)h * NWW + t;
#pragma unroll
    for (int c = 0; c < CC; ++c) {
        float v = lds[t * (CC + 1) + c];  // bank (t+c)%32 -> conflict-free
        out[obase + (size_t)c * PLANE] = v;
    }
}

extern "C" void kernel_launch(void* const* d_in, const int* in_sizes, int n_in,
                              void* d_out, int out_size, void* d_ws, size_t ws_size,
                              hipStream_t stream) {
    const float* features = (const float*)d_in[0];
    const int* coords = (const int*)d_in[1];
    float* out = (float*)d_out;
    const int N = in_sizes[1] / 3;

    const size_t invmap_bytes = (size_t)NCELLS * sizeof(int);       // 4 MiB
    const size_t featT_bytes = (size_t)N * CC * sizeof(float);      // ~115 MB

    if (ws_size < invmap_bytes + featT_bytes) {
        // Fallback: direct scatter (correct, slower).
        hipMemsetAsync(d_out, 0, (size_t)out_size * sizeof(float), stream);
        int blocks = (N + 255) / 256;
        pss_scatter_direct<<<blocks, 256, 0, stream>>>(features, coords, out, N);
        return;
    }

    int* invmap = (int*)d_ws;
    float* featT = (float*)((char*)d_ws + invmap_bytes);

    // Zero invmap (0 == empty cell).
    hipMemsetAsync(invmap, 0, invmap_bytes, stream);

    pss_invmap<<<(N + 255) / 256, 256, 0, stream>>>(coords, invmap, N);

    pss_transpose<<<(N + 127) / 128, 128, 0, stream>>>(features, featT, N);

    pss_gather_emit<<<BB * NHH, 256, 0, stream>>>(featT, invmap, out);
}